// Round 20
// baseline (66.342 us; speedup 1.0000x reference)
//
#include <hip/hip_runtime.h>

// BeamDelay2AntFreq: (256,32,8,4,2,48) complex -> ifft4(V) -> ifft8(H) -> fft48(t),
// fftshifts folded into (-1)^{h+v+f}; ortho norm 1/sqrt(1536).
// OUTPUT: interleaved bf16 pairs IMAG FIRST: dword = im | (re<<16), (b,c,row,f) order.
// R20: RP=52 (16B-aligned rows, still 6 blocks/CU at 26.6KB) + vectorized V/H:
// V = 192 threads, float4 global loads (dense) + b128 LDS writes;
// H = 96 threads, b128 LDS reads/writes. A/B unchanged. 2 barriers.

namespace {

constexpr int RP = 52;       // T/S row stride (floats): 16B aligned, span 48 < 52
constexpr float NORM = 0.02551551815399144f;  // 1/sqrt(1536)
constexpr float R2  = 0.70710678f;            // 1/sqrt(2)
constexpr float C30 = 0.86602540f;            // cos(30)

constexpr float COS48[48] = {
  1.0f,        0.99144486f,  0.96592583f,  0.92387953f,  0.86602540f,  0.79335334f,
  0.70710678f, 0.60876143f,  0.5f,         0.38268343f,  0.25881905f,  0.13052619f,
  0.0f,       -0.13052619f, -0.25881905f, -0.38268343f, -0.5f,        -0.60876143f,
 -0.70710678f,-0.79335334f, -0.86602540f, -0.92387953f, -0.96592583f, -0.99144486f,
 -1.0f,       -0.99144486f, -0.96592583f, -0.92387953f, -0.86602540f, -0.79335334f,
 -0.70710678f,-0.60876143f, -0.5f,        -0.38268343f, -0.25881905f, -0.13052619f,
  0.0f,        0.13052619f,  0.25881905f,  0.38268343f,  0.5f,         0.60876143f,
  0.70710678f, 0.79335334f,  0.86602540f,  0.92387953f,  0.96592583f,  0.99144486f
};
constexpr float SIN48[48] = {
  0.0f,        0.13052619f,  0.25881905f,  0.38268343f,  0.5f,         0.60876143f,
  0.70710678f, 0.79335334f,  0.86602540f,  0.92387953f,  0.96592583f,  0.99144486f,
  1.0f,        0.99144486f,  0.96592583f,  0.92387953f,  0.86602540f,  0.79335334f,
  0.70710678f, 0.60876143f,  0.5f,         0.38268343f,  0.25881905f,  0.13052619f,
  0.0f,       -0.13052619f, -0.25881905f, -0.38268343f, -0.5f,        -0.60876143f,
 -0.70710678f,-0.79335334f, -0.86602540f, -0.92387953f, -0.96592583f, -0.99144486f,
 -1.0f,       -0.99144486f, -0.86602540f - 0.0f, -0.92387953f, -0.96592583f, -0.99144486f,
 -0.70710678f,-0.60876143f, -0.5f,        -0.38268343f, -0.25881905f, -0.13052619f
};
// NOTE: SIN48 row 7 above would be wrong — use the exact table (fixed below).

constexpr float SIN48_FIX[48] = {
  0.0f,        0.13052619f,  0.25881905f,  0.38268343f,  0.5f,         0.60876143f,
  0.70710678f, 0.79335334f,  0.86602540f,  0.92387953f,  0.96592583f,  0.99144486f,
  1.0f,        0.99144486f,  0.96592583f,  0.92387953f,  0.86602540f,  0.79335334f,
  0.70710678f, 0.60876143f,  0.5f,         0.38268343f,  0.25881905f,  0.13052619f,
  0.0f,       -0.13052619f, -0.25881905f, -0.38268343f, -0.5f,        -0.60876143f,
 -0.70710678f,-0.79335334f, -0.86602540f, -0.92387953f, -0.96592583f, -0.99144486f,
 -1.0f,       -0.99144486f, -0.96592583f, -0.92387953f, -0.86602540f, -0.79335334f,
 -0.70710678f,-0.60876143f, -0.5f,        -0.38268343f, -0.25881905f, -0.13052619f
};

__device__ __forceinline__ unsigned bf16_rne(float x) {
  unsigned u = __float_as_uint(x);
  u += 0x7FFFu + ((u >> 16) & 1u);
  return u >> 16;
}

__device__ __forceinline__ float4 f4add(float4 a, float4 b) {
  return make_float4(a.x + b.x, a.y + b.y, a.z + b.z, a.w + b.w);
}
__device__ __forceinline__ float4 f4sub(float4 a, float4 b) {
  return make_float4(a.x - b.x, a.y - b.y, a.z - b.z, a.w - b.w);
}
__device__ __forceinline__ float4 f4scale(float4 a, float s) {
  return make_float4(a.x * s, a.y * s, a.z * s, a.w * s);
}

__global__ __launch_bounds__(256, 6)
void bd2af_kernel(const float* __restrict__ xr, const float* __restrict__ xi,
                  unsigned* __restrict__ out, int nbc) {
  __shared__ __align__(16) float Tr[64 * RP], Ti[64 * RP];  // X->T1->Y->S overlay

  const int tid = threadIdx.x;
  const int bc = blockIdx.x;
  if (bc >= nbc) return;

  const float* gxr = xr + (size_t)bc * 3072;
  const float* gxi = xi + (size_t)bc * 3072;

  // ---- V phase (192 threads): float4 global loads, 4-pt inverse FFT, b128 writes ----
  if (tid < 192) {
    const int hq = tid / 24;           // 0..7
    const int p  = (tid / 12) % 2;
    const int tq = tid % 12;
    const int col = 4 * tq;
    const int rowb = hq * 8 + p;       // rows rowb + 2V
    const float4 x0r = *reinterpret_cast<const float4*>(&gxr[(rowb + 0) * 48 + col]);
    const float4 x0i = *reinterpret_cast<const float4*>(&gxi[(rowb + 0) * 48 + col]);
    const float4 x1r = *reinterpret_cast<const float4*>(&gxr[(rowb + 2) * 48 + col]);
    const float4 x1i = *reinterpret_cast<const float4*>(&gxi[(rowb + 2) * 48 + col]);
    const float4 x2r = *reinterpret_cast<const float4*>(&gxr[(rowb + 4) * 48 + col]);
    const float4 x2i = *reinterpret_cast<const float4*>(&gxi[(rowb + 4) * 48 + col]);
    const float4 x3r = *reinterpret_cast<const float4*>(&gxr[(rowb + 6) * 48 + col]);
    const float4 x3i = *reinterpret_cast<const float4*>(&gxi[(rowb + 6) * 48 + col]);
    const float4 e0r = f4add(x0r, x2r), e0i = f4add(x0i, x2i);
    const float4 e1r = f4sub(x0r, x2r), e1i = f4sub(x0i, x2i);
    const float4 o0r = f4add(x1r, x3r), o0i = f4add(x1i, x3i);
    const float4 o1r = f4sub(x1r, x3r), o1i = f4sub(x1i, x3i);
    *reinterpret_cast<float4*>(&Tr[(rowb + 0) * RP + col]) = f4add(e0r, o0r);
    *reinterpret_cast<float4*>(&Ti[(rowb + 0) * RP + col]) = f4add(e0i, o0i);
    *reinterpret_cast<float4*>(&Tr[(rowb + 2) * RP + col]) = f4sub(e1r, o1i);  // +i*o1
    *reinterpret_cast<float4*>(&Ti[(rowb + 2) * RP + col]) = f4add(e1i, o1r);
    *reinterpret_cast<float4*>(&Tr[(rowb + 4) * RP + col]) = f4sub(e0r, o0r);
    *reinterpret_cast<float4*>(&Ti[(rowb + 4) * RP + col]) = f4sub(e0i, o0i);
    *reinterpret_cast<float4*>(&Tr[(rowb + 6) * RP + col]) = f4add(e1r, o1i);  // -i*o1
    *reinterpret_cast<float4*>(&Ti[(rowb + 6) * RP + col]) = f4sub(e1i, o1r);
  }
  __syncthreads();

  // ---- H phase (96 threads): b128 LDS, 8-pt inverse FFT in-place, (-1)^{h'+v'} ----
  if (tid < 96) {
    const int vq = tid / 24;           // 0..3
    const int p  = (tid / 12) % 2;
    const int tq = tid % 12;
    const int col = 4 * tq;
    const int rowb = 2 * vq + p;       // rows rowb + 8H
    const float sgnE = (vq & 1) ? -1.f : 1.f;
    const float sgnO = -sgnE;
    const float4 t0r = *reinterpret_cast<const float4*>(&Tr[(rowb +  0) * RP + col]);
    const float4 t0i = *reinterpret_cast<const float4*>(&Ti[(rowb +  0) * RP + col]);
    const float4 t1r = *reinterpret_cast<const float4*>(&Tr[(rowb +  8) * RP + col]);
    const float4 t1i = *reinterpret_cast<const float4*>(&Ti[(rowb +  8) * RP + col]);
    const float4 t2r = *reinterpret_cast<const float4*>(&Tr[(rowb + 16) * RP + col]);
    const float4 t2i = *reinterpret_cast<const float4*>(&Ti[(rowb + 16) * RP + col]);
    const float4 t3r = *reinterpret_cast<const float4*>(&Tr[(rowb + 24) * RP + col]);
    const float4 t3i = *reinterpret_cast<const float4*>(&Ti[(rowb + 24) * RP + col]);
    const float4 t4r = *reinterpret_cast<const float4*>(&Tr[(rowb + 32) * RP + col]);
    const float4 t4i = *reinterpret_cast<const float4*>(&Ti[(rowb + 32) * RP + col]);
    const float4 t5r = *reinterpret_cast<const float4*>(&Tr[(rowb + 40) * RP + col]);
    const float4 t5i = *reinterpret_cast<const float4*>(&Ti[(rowb + 40) * RP + col]);
    const float4 t6r = *reinterpret_cast<const float4*>(&Tr[(rowb + 48) * RP + col]);
    const float4 t6i = *reinterpret_cast<const float4*>(&Ti[(rowb + 48) * RP + col]);
    const float4 t7r = *reinterpret_cast<const float4*>(&Tr[(rowb + 56) * RP + col]);
    const float4 t7i = *reinterpret_cast<const float4*>(&Ti[(rowb + 56) * RP + col]);
    // evens -> inverse DFT4
    const float4 e0r = f4add(t0r, t4r), e0i = f4add(t0i, t4i);
    const float4 e1r = f4sub(t0r, t4r), e1i = f4sub(t0i, t4i);
    const float4 o0r = f4add(t2r, t6r), o0i = f4add(t2i, t6i);
    const float4 o1r = f4sub(t2r, t6r), o1i = f4sub(t2i, t6i);
    const float4 E0r = f4add(e0r, o0r), E0i = f4add(e0i, o0i);
    const float4 E2r = f4sub(e0r, o0r), E2i = f4sub(e0i, o0i);
    const float4 E1r = f4sub(e1r, o1i), E1i = f4add(e1i, o1r);   // e1 + i o1
    const float4 E3r = f4add(e1r, o1i), E3i = f4sub(e1i, o1r);   // e1 - i o1
    // odds -> inverse DFT4
    const float4 f0r = f4add(t1r, t5r), f0i = f4add(t1i, t5i);
    const float4 f1r = f4sub(t1r, t5r), f1i = f4sub(t1i, t5i);
    const float4 g0r = f4add(t3r, t7r), g0i = f4add(t3i, t7i);
    const float4 g1r = f4sub(t3r, t7r), g1i = f4sub(t3i, t7i);
    const float4 O0r = f4add(f0r, g0r), O0i = f4add(f0i, g0i);
    const float4 O2r = f4sub(f0r, g0r), O2i = f4sub(f0i, g0i);
    const float4 O1r = f4sub(f1r, g1i), O1i = f4add(f1i, g1r);
    const float4 O3r = f4add(f1r, g1i), O3i = f4sub(f1i, g1r);
    // twiddles: W1 = (1+i)/sqrt2 * O1 ; W3 = (-1+i)/sqrt2 * O3
    const float4 W1r = f4scale(f4sub(O1r, O1i), R2);
    const float4 W1i = f4scale(f4add(O1r, O1i), R2);
    const float4 W3r = f4scale(f4add(O3r, O3i), -R2);
    const float4 W3i = f4scale(f4sub(O3r, O3i), R2);
    *reinterpret_cast<float4*>(&Tr[(rowb +  0) * RP + col]) = f4scale(f4add(E0r, O0r), sgnE);
    *reinterpret_cast<float4*>(&Ti[(rowb +  0) * RP + col]) = f4scale(f4add(E0i, O0i), sgnE);
    *reinterpret_cast<float4*>(&Tr[(rowb + 32) * RP + col]) = f4scale(f4sub(E0r, O0r), sgnE);
    *reinterpret_cast<float4*>(&Ti[(rowb + 32) * RP + col]) = f4scale(f4sub(E0i, O0i), sgnE);
    *reinterpret_cast<float4*>(&Tr[(rowb + 16) * RP + col]) = f4scale(f4sub(E2r, O2i), sgnE);
    *reinterpret_cast<float4*>(&Ti[(rowb + 16) * RP + col]) = f4scale(f4add(E2i, O2r), sgnE);
    *reinterpret_cast<float4*>(&Tr[(rowb + 48) * RP + col]) = f4scale(f4add(E2r, O2i), sgnE);
    *reinterpret_cast<float4*>(&Ti[(rowb + 48) * RP + col]) = f4scale(f4sub(E2i, O2r), sgnE);
    *reinterpret_cast<float4*>(&Tr[(rowb +  8) * RP + col]) = f4scale(f4add(E1r, W1r), sgnO);
    *reinterpret_cast<float4*>(&Ti[(rowb +  8) * RP + col]) = f4scale(f4add(E1i, W1i), sgnO);
    *reinterpret_cast<float4*>(&Tr[(rowb + 40) * RP + col]) = f4scale(f4sub(E1r, W1r), sgnO);
    *reinterpret_cast<float4*>(&Ti[(rowb + 40) * RP + col]) = f4scale(f4sub(E1i, W1i), sgnO);
    *reinterpret_cast<float4*>(&Tr[(rowb + 24) * RP + col]) = f4scale(f4add(E3r, W3r), sgnO);
    *reinterpret_cast<float4*>(&Ti[(rowb + 24) * RP + col]) = f4scale(f4add(E3i, W3i), sgnO);
    *reinterpret_cast<float4*>(&Tr[(rowb + 56) * RP + col]) = f4scale(f4sub(E3r, W3r), sgnO);
    *reinterpret_cast<float4*>(&Ti[(rowb + 56) * RP + col]) = f4scale(f4sub(E3i, W3i), sgnO);
  }
  __syncthreads();

  // ---- Phase A: radix-12 DFT per (row, b); S overlays T row-in-place ----
  {
    const int r = tid >> 2;
    const int b = tid & 3;
    float zr[12], zi[12];
#pragma unroll
    for (int a = 0; a < 12; ++a) {
      zr[a] = Tr[r * RP + 4 * a + b];
      zi[a] = Ti[r * RP + 4 * a + b];
    }
    float h0r[3], h0i[3], h1r[3], h1i[3], h2r[3], h2i[3], h3r[3], h3i[3];
#pragma unroll
    for (int a2 = 0; a2 < 3; ++a2) {
      const float e0r = zr[a2] + zr[a2 + 6], e0i = zi[a2] + zi[a2 + 6];
      const float e1r = zr[a2] - zr[a2 + 6], e1i = zi[a2] - zi[a2 + 6];
      const float o0r = zr[a2 + 3] + zr[a2 + 9], o0i = zi[a2 + 3] + zi[a2 + 9];
      const float o1r = zr[a2 + 3] - zr[a2 + 9], o1i = zi[a2 + 3] - zi[a2 + 9];
      h0r[a2] = e0r + o0r;  h0i[a2] = e0i + o0i;
      h2r[a2] = e0r - o0r;  h2i[a2] = e0i - o0i;
      h1r[a2] = e1r + o1i;  h1i[a2] = e1i - o1r;   // e1 - i o1 (forward)
      h3r[a2] = e1r - o1i;  h3i[a2] = e1i + o1r;   // e1 + i o1
    }
    {
      float a, bb;
      a = h1r[1]; bb = h1i[1];
      h1r[1] = C30 * a + 0.5f * bb;  h1i[1] = C30 * bb - 0.5f * a;
      a = h2r[1]; bb = h2i[1];
      h2r[1] = 0.5f * a + C30 * bb;  h2i[1] = 0.5f * bb - C30 * a;
      a = h3r[1]; bb = h3i[1];
      h3r[1] = bb;                   h3i[1] = -a;
      a = h1r[2]; bb = h1i[2];
      h1r[2] = 0.5f * a + C30 * bb;  h1i[2] = 0.5f * bb - C30 * a;
      a = h2r[2]; bb = h2i[2];
      h2r[2] = -0.5f * a + C30 * bb; h2i[2] = -0.5f * bb - C30 * a;
      h3r[2] = -h3r[2];              h3i[2] = -h3i[2];
    }
    float s_r[12], s_i[12];
#define DFT3(J1, HR, HI)                                                    \
    {                                                                       \
      const float tr_ = HR[1] + HR[2], ti_ = HI[1] + HI[2];                 \
      const float dr_ = HR[1] - HR[2], di_ = HI[1] - HI[2];                 \
      const float mr_ = HR[0] - 0.5f * tr_, mi_ = HI[0] - 0.5f * ti_;       \
      const float wr_ = C30 * dr_, wi_ = C30 * di_;                         \
      s_r[J1]     = HR[0] + tr_;  s_i[J1]     = HI[0] + ti_;                \
      s_r[J1 + 4] = mr_ + wi_;    s_i[J1 + 4] = mi_ - wr_;                  \
      s_r[J1 + 8] = mr_ - wi_;    s_i[J1 + 8] = mi_ + wr_;                  \
    }
    DFT3(0, h0r, h0i)
    DFT3(1, h1r, h1i)
    DFT3(2, h2r, h2i)
    DFT3(3, h3r, h3i)
#undef DFT3
#pragma unroll
    for (int j = 0; j < 12; ++j) {
      Tr[r * RP + b * 12 + j] = s_r[j];
      Ti[r * RP + b * 12 + j] = s_i[j];
    }
  }
  // NO barrier: phase B reads S rows written by the same wave.

  // ---- Phase B: combine 4 b-slices with W48 twiddles, pack, direct store ----
  {
    const int r = tid >> 2;
    const int c = tid & 3;
    const float a1r = (c == 0) ? 1.f : ((c == 2) ? -1.f : 0.f);
    const float a1i = (c == 1) ? -1.f : ((c == 3) ? 1.f : 0.f);
    const float s2  = (c & 1) ? -1.f : 1.f;
    float or_[12], oi_[12];
#pragma unroll
    for (int j = 0; j < 12; ++j) {
      or_[j] = Tr[r * RP + j];
      oi_[j] = Ti[r * RP + j];
    }
#pragma unroll
    for (int j = 0; j < 12; ++j) {   // b = 1: (-i)^c * S1*W48^j
      const float wr = COS48[j], wi = -SIN48_FIX[j];
      const float sr = Tr[r * RP + 12 + j], si = Ti[r * RP + 12 + j];
      const float tr = sr * wr - si * wi, ti = sr * wi + si * wr;
      or_[j] += a1r * tr - a1i * ti;
      oi_[j] += a1r * ti + a1i * tr;
    }
#pragma unroll
    for (int j = 0; j < 12; ++j) {   // b = 2: (-1)^c * S2*W48^{2j}
      const float wr = COS48[(2 * j) % 48], wi = -SIN48_FIX[(2 * j) % 48];
      const float sr = Tr[r * RP + 24 + j], si = Ti[r * RP + 24 + j];
      const float tr = sr * wr - si * wi, ti = sr * wi + si * wr;
      or_[j] += s2 * tr;
      oi_[j] += s2 * ti;
    }
#pragma unroll
    for (int j = 0; j < 12; ++j) {   // b = 3: (i)^c * S3*W48^{3j}
      const float wr = COS48[(3 * j) % 48], wi = -SIN48_FIX[(3 * j) % 48];
      const float sr = Tr[r * RP + 36 + j], si = Ti[r * RP + 36 + j];
      const float tr = sr * wr - si * wi, ti = sr * wi + si * wr;
      or_[j] += a1r * tr + a1i * ti;
      oi_[j] += a1r * ti - a1i * tr;
    }
    unsigned pk[12];
#pragma unroll
    for (int j = 0; j < 12; ++j) {
      const float s = (j & 1) ? -NORM : NORM;   // (-1)^f = (-1)^j since f = 12c+j
      pk[j] = bf16_rne(oi_[j] * s) | (bf16_rne(or_[j] * s) << 16);
    }
    unsigned* og = out + (size_t)bc * 3072 + r * 48 + c * 12;
    *reinterpret_cast<uint4*>(og)     = make_uint4(pk[0], pk[1], pk[2],  pk[3]);
    *reinterpret_cast<uint4*>(og + 4) = make_uint4(pk[4], pk[5], pk[6],  pk[7]);
    *reinterpret_cast<uint4*>(og + 8) = make_uint4(pk[8], pk[9], pk[10], pk[11]);
  }
}

} // namespace

extern "C" void kernel_launch(void* const* d_in, const int* in_sizes, int n_in,
                              void* d_out, int out_size, void* d_ws, size_t ws_size,
                              hipStream_t stream) {
  const float* xr = (const float*)d_in[0];   // dict order: x_real first
  const float* xi = (const float*)d_in[1];
  unsigned* out = (unsigned*)d_out;          // dword = im(bf16) | re(bf16)<<16
  const int nbc = in_sizes[0] / 3072;        // 8192 blocks of (8*4*2*48)
  bd2af_kernel<<<nbc, 256, 0, stream>>>(xr, xi, out, nbc);
}